// Round 4
// baseline (65.484 us; speedup 1.0000x reference)
//
#include <hip/hip_runtime.h>
#include <math.h>

#define ND 64
#define NPTS (4 * ND * ND * ND)   // 1,048,576

// Tile: 8x8x16 owned points + halo 2 -> 12x12x20 cells, float3 AoS.
// LDS dword strides (z-row padded to odd 61 to mix bank parity):
#define DSX 732   // 12*61
#define DSY 61    // 20*3 + 1 pad
#define DSZ 3
#define LDS_DWORDS (11*DSX + 11*DSY + 19*DSZ + 3)   // 8783

// jnp.gradient edge handling == uniform central diff on extrapolated ghosts:
//   ghost(-1) = 2 f(0) - f(1); ghost(-2) = 4 f(0) - 4 f(1) + f(2)  (and mirrored
//   at the +64 side). Multi-axis ghosts are the tensor product (verified r3,
//   absmax 0.0). axis_w returns the taps+weights for one axis.
__device__ __forceinline__ void axis_w(int g, int idx[3], float w[3], int& n) {
    if (g >= 0 && g < ND) { idx[0] = g; idx[1] = 0; idx[2] = 0; w[0] = 1.f; w[1] = 0.f; w[2] = 0.f; n = 1; }
    else if (g == -1)     { idx[0] = 0; idx[1] = 1; idx[2] = 0; w[0] = 2.f; w[1] = -1.f; w[2] = 0.f; n = 2; }
    else if (g == -2)     { idx[0] = 0; idx[1] = 1; idx[2] = 2; w[0] = 4.f; w[1] = -4.f; w[2] = 1.f; n = 3; }
    else if (g == ND)     { idx[0] = ND-1; idx[1] = ND-2; idx[2] = 0;    w[0] = 2.f; w[1] = -1.f; w[2] = 0.f; n = 2; }
    else                  { idx[0] = ND-1; idx[1] = ND-2; idx[2] = ND-3; w[0] = 4.f; w[1] = -4.f; w[2] = 1.f; n = 3; }
}

// physics residual norm at one point; H is symmetric, stored [c][6]:
// 0=xx 1=yy 2=zz 3=xy 4=xz 5=yz
__device__ __forceinline__ float phys_norm(const float F[3][3], const float H[3][6]) {
    constexpr int SYM[3][3] = {{0, 3, 4}, {3, 1, 5}, {4, 5, 2}};

    float cof[3][3];
#pragma unroll
    for (int i = 0; i < 3; i++) {
        const int i1 = (i + 1) % 3, i2 = (i + 2) % 3;
#pragma unroll
        for (int j = 0; j < 3; j++) {
            const int j1 = (j + 1) % 3, j2 = (j + 2) % 3;
            cof[i][j] = F[i1][j1] * F[i2][j2] - F[i1][j2] * F[i2][j1];
        }
    }

    float gc0[3][3], trg[3];
#pragma unroll
    for (int m = 0; m < 3; m++) {
        const int m1 = (m + 1) % 3, m2 = (m + 2) % 3;
        trg[m] = 0.0f;
#pragma unroll
        for (int i = 0; i < 3; i++) {
            const int i1 = (i + 1) % 3, i2 = (i + 2) % 3;
#pragma unroll
            for (int j = 0; j < 3; j++) {
                if (i == 0 || i == j) {
                    const float g = F[m2][i2] * H[m1][SYM[i1][j]] + F[m1][i1] * H[m2][SYM[i2][j]]
                                  - F[m2][i1] * H[m1][SYM[i2][j]] - F[m1][i2] * H[m2][SYM[i1][j]];
                    if (i == 0) gc0[m][j] = g;
                    if (i == j) trg[m] += g;
                }
            }
        }
    }

    const float J = F[0][0] * cof[0][0] + F[1][0] * cof[1][0] + F[2][0] * cof[2][0] + 1e-8f;
    const float invJ = 1.0f / J;

    float gJ[3];
#pragma unroll
    for (int j = 0; j < 3; j++) {
        gJ[j] = cof[0][0] * H[0][SYM[0][j]] + cof[1][0] * H[1][SYM[0][j]] + cof[2][0] * H[2][SYM[0][j]]
              + gc0[0][j] * F[0][0] + gc0[1][j] * F[1][0] + gc0[2][j] * F[2][0];
    }

    const float MU = 1000.0f, LMBD = 5000.0f;
    const float halfL = 0.5f * LMBD * (J * J - 1.0f);
    float r[3];
#pragma unroll
    for (int m = 0; m < 3; m++) {
        const float s1 = gJ[0] * cof[m][0] + gJ[1] * cof[m][1] + gJ[2] * cof[m][2];
        const float divInv = -invJ * invJ * s1 + invJ * trg[m];
        const float divF = H[m][0] + H[m][1] + H[m][2];
        float v = MU * (divF - divInv) + halfL * divInv + LMBD * s1;
        r[m] = (v != v) ? 0.0f : v;   // NaN -> 0
    }
    return sqrtf(r[0] * r[0] + r[1] * r[1] + r[2] * r[2]);
}

__global__ __launch_bounds__(512) void phys_loss_kernel(
        const float* __restrict__ pred,
        const float* __restrict__ targ,
        float* __restrict__ out) {
    __shared__ float s[LDS_DWORDS];   // ~35.1 KB

    const int bid = blockIdx.x;
    const int zt = bid & 3, yt = (bid >> 2) & 7, xt = (bid >> 5) & 7, b = bid >> 8;
    const int t = threadIdx.x;
    const int tz2 = t & 7, ty = (t >> 3) & 7, tx = t >> 6;
    const int X0 = xt * 8, Y0 = yt * 8, Z0 = zt * 16;

    const float* __restrict__ pb = pred + (size_t)b * (ND * ND * ND * 3);

    // ---- staging: 12x12x20 cells, ghosts extrapolated directly from global ----
    for (int i = t; i < 12 * 12 * 20; i += 512) {
        const int lz = i % 20;
        const int rr = i / 20;
        const int ly = rr % 12;
        const int lx = rr / 12;
        const int gx = X0 + lx - 2, gy = Y0 + ly - 2, gz = Z0 + lz - 2;
        float v0, v1, v2;
        if (((gx | gy | gz) >= 0) && gx < ND && gy < ND && gz < ND) {
            const float* g = pb + (size_t)((gx * ND + gy) * ND + gz) * 3;
            v0 = g[0]; v1 = g[1]; v2 = g[2];
        } else {
            int ix[3], iy[3], iz[3], nx, ny, nz;
            float wx[3], wy[3], wz[3];
            axis_w(gx, ix, wx, nx);
            axis_w(gy, iy, wy, ny);
            axis_w(gz, iz, wz, nz);
            v0 = v1 = v2 = 0.f;
#pragma unroll
            for (int a = 0; a < 3; a++) if (a < nx) {
#pragma unroll
                for (int bb = 0; bb < 3; bb++) if (bb < ny) {
#pragma unroll
                    for (int cc = 0; cc < 3; cc++) if (cc < nz) {
                        const float ww = wx[a] * wy[bb] * wz[cc];
                        const float* g = pb + (size_t)((ix[a] * ND + iy[bb]) * ND + iz[cc]) * 3;
                        v0 += ww * g[0]; v1 += ww * g[1]; v2 += ww * g[2];
                    }
                }
            }
        }
        const int o = lx * DSX + ly * DSY + lz * DSZ;
        s[o] = v0; s[o + 1] = v1; s[o + 2] = v2;
    }
    __syncthreads();

    // ---- per-thread: two adjacent z points at local z = 2*tz2+2 (+1) ----
    const int base = (tx + 2) * DSX + (ty + 2) * DSY + (2 * tz2 + 2) * DSZ;

    float q[18];                       // (0,0) row, z-2..z+3
#pragma unroll
    for (int k = 0; k < 18; k++) q[k] = s[base - 6 + k];
    float ax[12], bx[12], ay[12], by[12];   // (±1,0),(0,±1) rows, z-1..z+2
#pragma unroll
    for (int k = 0; k < 12; k++) ax[k] = s[base + DSX - 3 + k];
#pragma unroll
    for (int k = 0; k < 12; k++) bx[k] = s[base - DSX - 3 + k];
#pragma unroll
    for (int k = 0; k < 12; k++) ay[k] = s[base + DSY - 3 + k];
#pragma unroll
    for (int k = 0; k < 12; k++) by[k] = s[base - DSY - 3 + k];
    float p2x[6], m2x[6], p2y[6], m2y[6];   // (±2,0),(0,±2), z..z+1
#pragma unroll
    for (int k = 0; k < 6; k++) p2x[k] = s[base + 2 * DSX + k];
#pragma unroll
    for (int k = 0; k < 6; k++) m2x[k] = s[base - 2 * DSX + k];
#pragma unroll
    for (int k = 0; k < 6; k++) p2y[k] = s[base + 2 * DSY + k];
#pragma unroll
    for (int k = 0; k < 6; k++) m2y[k] = s[base - 2 * DSY + k];
    float dpp[6], dpm[6], dmp[6], dmm[6];   // (±1,±1), z..z+1
#pragma unroll
    for (int k = 0; k < 6; k++) dpp[k] = s[base + DSX + DSY + k];
#pragma unroll
    for (int k = 0; k < 6; k++) dpm[k] = s[base + DSX - DSY + k];
#pragma unroll
    for (int k = 0; k < 6; k++) dmp[k] = s[base - DSX + DSY + k];
#pragma unroll
    for (int k = 0; k < 6; k++) dmm[k] = s[base - DSX - DSY + k];

    float F0[3][3], F1[3][3], H0[3][6], H1[3][6], c00[3], c01[3];
#pragma unroll
    for (int c = 0; c < 3; c++) {
        const float tm2 = q[c], tm1 = q[3 + c], t0 = q[6 + c], t1 = q[9 + c],
                    t2 = q[12 + c], t3 = q[15 + c];
        c00[c] = t0; c01[c] = t1;
        const float id0 = (c == 0) ? 1.f : 0.f;
        const float id1 = (c == 1) ? 1.f : 0.f;
        const float id2 = (c == 2) ? 1.f : 0.f;

        F0[c][2] = 0.5f * (t1 - tm1) + id2;
        F1[c][2] = 0.5f * (t2 - t0) + id2;
        H0[c][2] = 0.25f * (t2 + tm2) - 0.5f * t0;
        H1[c][2] = 0.25f * (t3 + tm1) - 0.5f * t1;

        const float axm = ax[c], ax0 = ax[3 + c], ax1 = ax[6 + c], ax2 = ax[9 + c];
        const float bxm = bx[c], bx0 = bx[3 + c], bx1 = bx[6 + c], bx2 = bx[9 + c];
        F0[c][0] = 0.5f * (ax0 - bx0) + id0;
        F1[c][0] = 0.5f * (ax1 - bx1) + id0;
        H0[c][4] = 0.25f * ((ax1 - bx1) - (axm - bxm));
        H1[c][4] = 0.25f * ((ax2 - bx2) - (ax0 - bx0));

        const float aym = ay[c], ay0 = ay[3 + c], ay1 = ay[6 + c], ay2 = ay[9 + c];
        const float bym = by[c], by0 = by[3 + c], by1 = by[6 + c], by2 = by[9 + c];
        F0[c][1] = 0.5f * (ay0 - by0) + id1;
        F1[c][1] = 0.5f * (ay1 - by1) + id1;
        H0[c][5] = 0.25f * ((ay1 - by1) - (aym - bym));
        H1[c][5] = 0.25f * ((ay2 - by2) - (ay0 - by0));

        H0[c][0] = 0.25f * (p2x[c] + m2x[c]) - 0.5f * t0;
        H1[c][0] = 0.25f * (p2x[3 + c] + m2x[3 + c]) - 0.5f * t1;
        H0[c][1] = 0.25f * (p2y[c] + m2y[c]) - 0.5f * t0;
        H1[c][1] = 0.25f * (p2y[3 + c] + m2y[3 + c]) - 0.5f * t1;

        H0[c][3] = 0.25f * ((dpp[c] - dmp[c]) - (dpm[c] - dmm[c]));
        H1[c][3] = 0.25f * ((dpp[3 + c] - dmp[3 + c]) - (dpm[3 + c] - dmm[3 + c]));
    }

    const float n0 = phys_norm(F0, H0);
    const float n1 = phys_norm(F1, H1);

    // ---- MSE: two float3 from targ (6 consecutive floats) ----
    const int gx = X0 + tx, gy = Y0 + ty, gz = Z0 + 2 * tz2;
    const float* tt = targ + (size_t)b * (ND * ND * ND * 3)
                    + (size_t)((gx * ND + gy) * ND + gz) * 3;
    float ssq = 0.f;
#pragma unroll
    for (int c = 0; c < 3; c++) {
        const float d0 = c00[c] - tt[c];
        const float d1 = c01[c] - tt[3 + c];
        ssq += d0 * d0 + d1 * d1;
    }

    const float invN = 1.0f / (float)NPTS;
    float val = 0.5f * ssq * (invN * (1.0f / 3.0f)) + 0.5f * (n0 + n1) * invN;

    // ---- reduction ----
#pragma unroll
    for (int off = 32; off > 0; off >>= 1) val += __shfl_down(val, off, 64);

    __shared__ float wsum[8];
    const int lane = t & 63;
    const int wid = t >> 6;
    if (lane == 0) wsum[wid] = val;
    __syncthreads();
    if (t == 0) {
        float acc = 0.0f;
#pragma unroll
        for (int w = 0; w < 8; w++) acc += wsum[w];
        atomicAdd(out, acc);
    }
}

extern "C" void kernel_launch(void* const* d_in, const int* in_sizes, int n_in,
                              void* d_out, int out_size, void* d_ws, size_t ws_size,
                              hipStream_t stream) {
    const float* pred = (const float*)d_in[0];
    const float* targ = (const float*)d_in[1];
    float* out = (float*)d_out;

    hipMemsetAsync(out, 0, sizeof(float), stream);

    const int blocks = 4 * 8 * 8 * 4;   // 1024
    phys_loss_kernel<<<blocks, 512, 0, stream>>>(pred, targ, out);
}

// Round 5
// 40.285 us; speedup vs baseline: 1.6255x; 1.6255x over previous
//
#include <hip/hip_runtime.h>
#include <math.h>

#define ND 64
#define NPTS (4 * ND * ND * ND)   // 1,048,576
#define SXG (ND * ND * 3)         // 12288
#define SYG (ND * 3)              // 192

struct f3 { float x, y, z; };

__device__ __forceinline__ f3 f3fma2(float a, const f3& X, float s, const f3& Y) {
    f3 r; r.x = a * X.x + s * Y.x; r.y = a * X.y + s * Y.y; r.z = a * X.z + s * Y.z; return r;
}
__device__ __forceinline__ f3 f3c3(float a, const f3& X, float s, const f3& Y, float u, const f3& Z) {
    f3 r; r.x = a * X.x + s * Y.x + u * Z.x;
    r.y = a * X.y + s * Y.y + u * Z.y;
    r.z = a * X.z + s * Y.z + u * Z.z; return r;
}

// physics residual norm; H symmetric [c][6]: 0=xx 1=yy 2=zz 3=xy 4=xz 5=yz
__device__ __forceinline__ float phys_norm(const float F[3][3], const float H[3][6]) {
    constexpr int SYM[3][3] = {{0, 3, 4}, {3, 1, 5}, {4, 5, 2}};

    float cof[3][3];
#pragma unroll
    for (int i = 0; i < 3; i++) {
        const int i1 = (i + 1) % 3, i2 = (i + 2) % 3;
#pragma unroll
        for (int j = 0; j < 3; j++) {
            const int j1 = (j + 1) % 3, j2 = (j + 2) % 3;
            cof[i][j] = F[i1][j1] * F[i2][j2] - F[i1][j2] * F[i2][j1];
        }
    }

    float gc0[3][3], trg[3];
#pragma unroll
    for (int m = 0; m < 3; m++) {
        const int m1 = (m + 1) % 3, m2 = (m + 2) % 3;
        trg[m] = 0.0f;
#pragma unroll
        for (int i = 0; i < 3; i++) {
            const int i1 = (i + 1) % 3, i2 = (i + 2) % 3;
#pragma unroll
            for (int j = 0; j < 3; j++) {
                if (i == 0 || i == j) {
                    const float g = F[m2][i2] * H[m1][SYM[i1][j]] + F[m1][i1] * H[m2][SYM[i2][j]]
                                  - F[m2][i1] * H[m1][SYM[i2][j]] - F[m1][i2] * H[m2][SYM[i1][j]];
                    if (i == 0) gc0[m][j] = g;
                    if (i == j) trg[m] += g;
                }
            }
        }
    }

    const float J = F[0][0] * cof[0][0] + F[1][0] * cof[1][0] + F[2][0] * cof[2][0] + 1e-8f;
    const float invJ = 1.0f / J;

    float gJ[3];
#pragma unroll
    for (int j = 0; j < 3; j++) {
        gJ[j] = cof[0][0] * H[0][SYM[0][j]] + cof[1][0] * H[1][SYM[0][j]] + cof[2][0] * H[2][SYM[0][j]]
              + gc0[0][j] * F[0][0] + gc0[1][j] * F[1][0] + gc0[2][j] * F[2][0];
    }

    const float MU = 1000.0f, LMBD = 5000.0f;
    const float halfL = 0.5f * LMBD * (J * J - 1.0f);
    float r[3];
#pragma unroll
    for (int m = 0; m < 3; m++) {
        const float s1 = gJ[0] * cof[m][0] + gJ[1] * cof[m][1] + gJ[2] * cof[m][2];
        const float divInv = -invJ * invJ * s1 + invJ * trg[m];
        const float divF = H[m][0] + H[m][1] + H[m][2];
        float v = MU * (divF - divInv) + halfL * divInv + LMBD * s1;
        r[m] = (v != v) ? 0.0f : v;   // NaN -> 0
    }
    return sqrtf(r[0] * r[0] + r[1] * r[1] + r[2] * r[2]);
}

// one component: z-taps via wave shuffle (lane == z) with in-register ghost
// extrapolation at lanes 0,1,62,63 (jnp.gradient edge == ghost identities,
// verified r3); writes dU row G[3] and Hessian row Hr[6].
__device__ __forceinline__ void comp_row(
        float vC, float vXP, float vXM, float vYP, float vYM,
        float vXP2, float vXM2, float vYP2, float vYM2,
        float vPP, float vPM, float vMP, float vMM,
        int ip1, int im1, int ip2, int im2,
        bool l0, bool l1, bool l62, bool l63,
        float G[3], float Hr[6]) {
    // own column z+/-1, z+/-2
    const float d1r = __shfl(vC, ip1, 64), u1r = __shfl(vC, im1, 64);
    const float d2r = __shfl(vC, ip2, 64), u2r = __shfl(vC, im2, 64);
    const float d1 = l63 ? 2.f * vC - u1r : d1r;
    const float u1 = l0  ? 2.f * vC - d1r : u1r;
    const float d2 = l63 ? 4.f * vC - 4.f * u1r + u2r : (l62 ? 2.f * d1 - vC : d2r);
    const float u2 = l0  ? 4.f * vC - 4.f * d1r + d2r : (l1 ? 2.f * u1 - vC : u2r);

    // neighbor columns z+/-1 (for cross terms)
    float ad = __shfl(vXP, ip1, 64), au = __shfl(vXP, im1, 64);
    const float XPd = l63 ? 2.f * vXP - au : ad;
    const float XPu = l0  ? 2.f * vXP - ad : au;
    ad = __shfl(vXM, ip1, 64); au = __shfl(vXM, im1, 64);
    const float XMd = l63 ? 2.f * vXM - au : ad;
    const float XMu = l0  ? 2.f * vXM - ad : au;
    ad = __shfl(vYP, ip1, 64); au = __shfl(vYP, im1, 64);
    const float YPd = l63 ? 2.f * vYP - au : ad;
    const float YPu = l0  ? 2.f * vYP - ad : au;
    ad = __shfl(vYM, ip1, 64); au = __shfl(vYM, im1, 64);
    const float YMd = l63 ? 2.f * vYM - au : ad;
    const float YMu = l0  ? 2.f * vYM - ad : au;

    G[0] = 0.5f * (vXP - vXM);
    G[1] = 0.5f * (vYP - vYM);
    G[2] = 0.5f * (d1 - u1);
    Hr[0] = 0.25f * (vXP2 + vXM2) - 0.5f * vC;
    Hr[1] = 0.25f * (vYP2 + vYM2) - 0.5f * vC;
    Hr[2] = 0.25f * (d2 + u2) - 0.5f * vC;
    Hr[3] = 0.25f * ((vPP - vMP) - (vPM - vMM));
    Hr[4] = 0.25f * ((XPd - XMd) - (XPu - XMu));
    Hr[5] = 0.25f * ((YPd - YMd) - (YPu - YMu));
}

__global__ __launch_bounds__(512) void phys_loss_kernel(
        const float* __restrict__ pred,
        const float* __restrict__ targ,
        float* __restrict__ out) {
    const int t = threadIdx.x;
    const int lane = t & 63;
    const int wid = t >> 6;
    const int cid = blockIdx.x * 8 + wid;   // column id
    const int y = cid & 63;
    const int x = (cid >> 6) & 63;
    const int b = cid >> 12;
    const int z = lane;

    const float* __restrict__ pb = pred + (size_t)b * (ND * SXG);

    const int xp1 = min(x + 1, 63), xm1 = max(x - 1, 0);
    const int xp2 = min(x + 2, 63), xm2 = max(x - 2, 0);
    const int yp1 = min(y + 1, 63), ym1 = max(y - 1, 0);
    const int yp2 = min(y + 2, 63), ym2 = max(y - 2, 0);

#define LD(xx, yy) (*(const f3*)(pb + (size_t)((xx) * SXG + (yy) * SYG + z * 3)))
    f3 C  = LD(x, y);
    f3 XP = LD(xp1, y), XM = LD(xm1, y), XP2 = LD(xp2, y), XM2 = LD(xm2, y);
    f3 YP = LD(x, yp1), YM = LD(x, ym1), YP2 = LD(x, yp2), YM2 = LD(x, ym2);
    f3 PP = LD(xp1, yp1), PM = LD(xp1, ym1), MP = LD(xm1, yp1), MM = LD(xm1, ym1);
#undef LD

    // ---- y ghost fixups (wave-uniform) ----
    if (y == 0) {
        YM  = f3fma2(2.f, C, -1.f, YP);
        YM2 = f3c3(4.f, C, -4.f, YP, 1.f, YP2);
        PM  = f3fma2(2.f, XP, -1.f, PP);
        MM  = f3fma2(2.f, XM, -1.f, MP);
    } else if (y == 1) {
        YM2 = f3fma2(2.f, YM, -1.f, C);
    } else if (y == 62) {
        YP2 = f3fma2(2.f, YP, -1.f, C);
    } else if (y == 63) {
        YP  = f3fma2(2.f, C, -1.f, YM);
        YP2 = f3c3(4.f, C, -4.f, YM, 1.f, YM2);
        PP  = f3fma2(2.f, XP, -1.f, PM);
        MP  = f3fma2(2.f, XM, -1.f, MM);
    }
    // ---- x ghost fixups (wave-uniform; overwrite any garbage corners) ----
    if (x == 0) {
        XM  = f3fma2(2.f, C, -1.f, XP);
        XM2 = f3c3(4.f, C, -4.f, XP, 1.f, XP2);
        MP  = f3fma2(2.f, YP, -1.f, PP);
        MM  = f3fma2(2.f, YM, -1.f, PM);
    } else if (x == 1) {
        XM2 = f3fma2(2.f, XM, -1.f, C);
    } else if (x == 62) {
        XP2 = f3fma2(2.f, XP, -1.f, C);
    } else if (x == 63) {
        XP  = f3fma2(2.f, C, -1.f, XM);
        XP2 = f3c3(4.f, C, -4.f, XM, 1.f, XM2);
        PP  = f3fma2(2.f, YP, -1.f, MP);
        PM  = f3fma2(2.f, YM, -1.f, MM);
    }

    const bool l0 = (lane == 0), l1 = (lane == 1), l62 = (lane == 62), l63 = (lane == 63);
    const int ip1 = (lane + 1) & 63, im1 = (lane + 63) & 63;
    const int ip2 = (lane + 2) & 63, im2 = (lane + 62) & 63;

    float F[3][3], H[3][6], G[3];
    comp_row(C.x, XP.x, XM.x, YP.x, YM.x, XP2.x, XM2.x, YP2.x, YM2.x,
             PP.x, PM.x, MP.x, MM.x, ip1, im1, ip2, im2, l0, l1, l62, l63, G, H[0]);
    F[0][0] = G[0] + 1.f; F[0][1] = G[1]; F[0][2] = G[2];
    comp_row(C.y, XP.y, XM.y, YP.y, YM.y, XP2.y, XM2.y, YP2.y, YM2.y,
             PP.y, PM.y, MP.y, MM.y, ip1, im1, ip2, im2, l0, l1, l62, l63, G, H[1]);
    F[1][0] = G[0]; F[1][1] = G[1] + 1.f; F[1][2] = G[2];
    comp_row(C.z, XP.z, XM.z, YP.z, YM.z, XP2.z, XM2.z, YP2.z, YM2.z,
             PP.z, PM.z, MP.z, MM.z, ip1, im1, ip2, im2, l0, l1, l62, l63, G, H[2]);
    F[2][0] = G[0]; F[2][1] = G[1]; F[2][2] = G[2] + 1.f;

    const float nrm = phys_norm(F, H);

    // ---- MSE ----
    const f3 T = *(const f3*)(targ + (size_t)b * (ND * SXG)
                              + (size_t)(x * SXG + y * SYG + z * 3));
    const float dx = C.x - T.x, dy = C.y - T.y, dz = C.z - T.z;
    const float ssq = dx * dx + dy * dy + dz * dz;

    const float invN = 1.0f / (float)NPTS;
    float val = 0.5f * ssq * (invN * (1.0f / 3.0f)) + 0.5f * nrm * invN;

    // ---- reduction: wave shuffle, then LDS across 8 waves ----
#pragma unroll
    for (int off = 32; off > 0; off >>= 1) val += __shfl_down(val, off, 64);

    __shared__ float wsum[8];
    if (lane == 0) wsum[wid] = val;
    __syncthreads();
    if (t == 0) {
        float acc = 0.0f;
#pragma unroll
        for (int w = 0; w < 8; w++) acc += wsum[w];
        atomicAdd(out, acc);
    }
}

extern "C" void kernel_launch(void* const* d_in, const int* in_sizes, int n_in,
                              void* d_out, int out_size, void* d_ws, size_t ws_size,
                              hipStream_t stream) {
    const float* pred = (const float*)d_in[0];
    const float* targ = (const float*)d_in[1];
    float* out = (float*)d_out;

    hipMemsetAsync(out, 0, sizeof(float), stream);

    const int blocks = (4 * 64 * 64) / 8;   // 2048 blocks, 8 columns each
    phys_loss_kernel<<<blocks, 512, 0, stream>>>(pred, targ, out);
}